// Round 1
// baseline (52.994 us; speedup 1.0000x reference)
//
#include <hip/hip_runtime.h>

// Hard-coded combos from the reference:
//   combo i passes iff s[cls0] in [lo0,hi0] AND s[cls1] in [lo1,hi1]
//   judgement = any pass; first = lowest passing index
//   value = judgement ? SPEECH_SCORE[first] : 0
// SPEECH_SCORE entries are already exact to 2 decimals, so round(x*100)/100 == x.

__global__ void speech_judgement_kernel(const float* __restrict__ score,
                                        float* __restrict__ out) {
    if (threadIdx.x != 0 || blockIdx.x != 0) return;

    const float s0   = score[0];
    const float s2   = score[2];
    const float s3   = score[3];
    const float s5   = score[5];
    const float s36  = score[36];
    const float s132 = score[132];

    const bool in05_07 = (s0 >= 0.5f) && (s0 <= 0.7f);

    bool ok[6];
    ok[0] = (s0 >= 0.6f) && (s0 <= 1.0f) && (s0 >= 0.0f) && (s0 <= 1.0f);
    ok[1] = in05_07 && (s2   >= 0.3f) && (s2   <= 0.7f);
    ok[2] = in05_07 && (s3   >= 0.2f) && (s3   <= 0.5f);
    ok[3] = in05_07 && (s5   >= 0.2f) && (s5   <= 0.4f);
    ok[4] = in05_07 && (s132 >= 0.2f) && (s132 <= 0.5f);
    ok[5] = in05_07 && (s36  >= 0.1f) && (s36  <= 0.3f);

    const float speech_score[6] = {5.0f, 1.0f, 1.0f, 1.5f, 1.0f, 1.2f};

    bool judgement = false;
    float value = 0.0f;
    #pragma unroll
    for (int i = 0; i < 6; ++i) {
        if (ok[i]) { judgement = true; value = speech_score[i]; break; }
    }

    out[0] = judgement ? 1.0f : 0.0f;
    out[1] = value;
}

extern "C" void kernel_launch(void* const* d_in, const int* in_sizes, int n_in,
                              void* d_out, int out_size, void* d_ws, size_t ws_size,
                              hipStream_t stream) {
    const float* score = (const float*)d_in[0];
    float* out = (float*)d_out;
    speech_judgement_kernel<<<1, 64, 0, stream>>>(score, out);
}